// Round 1
// baseline (550.107 us; speedup 1.0000x reference)
//
#include <hip/hip_runtime.h>

// snn_layer: out[b,u,t] = (sum_f in[b,f,t] * w[f,u] > 1.0f) ? 1.0f : 0.0f
// B=128 F=512 T=256 U=1024, fp32 in/out.
// Per batch b: C[u][t] = (W^T X_b)[u][t], M=U=1024, N=T=256, K=F=512.
// fp32 -> no MFMA on CDNA4; vector-FMA GEMM.
// Block tile 128(u) x 128(t), BK=16, 256 threads, 8x8 accumulator per thread,
// register-prefetch of next global tile under compute (single LDS buffer).

#define BB 128
#define FF 512
#define TT 256
#define UU 1024

__global__ __launch_bounds__(256, 4)
void snn_gemm_kernel(const float* __restrict__ in, const float* __restrict__ w,
                     float* __restrict__ out) {
    // [k][m]/[k][n] layouts: both tiles load from global with natural
    // contiguity (u contiguous in w, t contiguous in in) -> no transpose.
    __shared__ float As[16][128];  // A = W^T tile: As[k][m], m = u - u0
    __shared__ float Bs[16][128];  // B = X tile:   Bs[k][n], n = t - t0

    const int b  = blockIdx.z;
    const int u0 = blockIdx.y * 128;
    const int t0 = blockIdx.x * 128;

    const float* __restrict__ inb  = in  + (size_t)b * FF * TT;
    float* __restrict__       outb = out + (size_t)b * UU * TT;

    const int tid = threadIdx.x;
    const int tx  = tid & 15;   // n-dim (t)
    const int ty  = tid >> 4;   // m-dim (u)

    // Staging: tile = 16x128 floats = 512 float4; 256 threads x 2 float4.
    // float4 slot q in {tid, tid+256}: k = q>>5, col = (q&31)*4.
    const int k0 = tid >> 5;          // 0..7
    const int c0 = (tid & 31) * 4;    // 0..124
    const int k1 = k0 + 8;            // 8..15

    float acc[8][8];
#pragma unroll
    for (int i = 0; i < 8; i++)
#pragma unroll
        for (int j = 0; j < 8; j++) acc[i][j] = 0.0f;

    // Prefetch first K-tile into registers.
    float4 a_r0 = *(const float4*)&w[(size_t)k0 * UU + u0 + c0];
    float4 a_r1 = *(const float4*)&w[(size_t)k1 * UU + u0 + c0];
    float4 b_r0 = *(const float4*)&inb[k0 * TT + t0 + c0];
    float4 b_r1 = *(const float4*)&inb[k1 * TT + t0 + c0];

    for (int f0 = 0; f0 < FF; f0 += 16) {
        // Commit staged registers to LDS.
        *(float4*)&As[k0][c0] = a_r0;
        *(float4*)&As[k1][c0] = a_r1;
        *(float4*)&Bs[k0][c0] = b_r0;
        *(float4*)&Bs[k1][c0] = b_r1;
        __syncthreads();

        // Prefetch next K-tile (hidden under the 1024-FMA compute below).
        if (f0 + 16 < FF) {
            const int fn = f0 + 16;
            a_r0 = *(const float4*)&w[(size_t)(fn + k0) * UU + u0 + c0];
            a_r1 = *(const float4*)&w[(size_t)(fn + k1) * UU + u0 + c0];
            b_r0 = *(const float4*)&inb[(fn + k0) * TT + t0 + c0];
            b_r1 = *(const float4*)&inb[(fn + k1) * TT + t0 + c0];
        }

#pragma unroll
        for (int k = 0; k < 16; k++) {
            const float4 a0 = *(const float4*)&As[k][ty * 4];
            const float4 a1 = *(const float4*)&As[k][ty * 4 + 64];
            const float4 v0 = *(const float4*)&Bs[k][tx * 4];
            const float4 v1 = *(const float4*)&Bs[k][tx * 4 + 64];
            const float am[8] = {a0.x, a0.y, a0.z, a0.w, a1.x, a1.y, a1.z, a1.w};
            const float bn[8] = {v0.x, v0.y, v0.z, v0.w, v1.x, v1.y, v1.z, v1.w};
#pragma unroll
            for (int i = 0; i < 8; i++)
#pragma unroll
                for (int j = 0; j < 8; j++)
                    acc[i][j] = fmaf(am[i], bn[j], acc[i][j]);
        }
        __syncthreads();
    }

    // Epilogue: heaviside(h - 1) == (h > 1.0f), exact for fp32 (Sterbenz on [0.5,2]).
#pragma unroll
    for (int i = 0; i < 8; i++) {
        const int m = (i < 4) ? (ty * 4 + i) : (64 + ty * 4 + i - 4);
        float* __restrict__ orow = outb + (size_t)(u0 + m) * TT + t0;
        float4 o0, o1;
        o0.x = acc[i][0] > 1.0f ? 1.0f : 0.0f;
        o0.y = acc[i][1] > 1.0f ? 1.0f : 0.0f;
        o0.z = acc[i][2] > 1.0f ? 1.0f : 0.0f;
        o0.w = acc[i][3] > 1.0f ? 1.0f : 0.0f;
        o1.x = acc[i][4] > 1.0f ? 1.0f : 0.0f;
        o1.y = acc[i][5] > 1.0f ? 1.0f : 0.0f;
        o1.z = acc[i][6] > 1.0f ? 1.0f : 0.0f;
        o1.w = acc[i][7] > 1.0f ? 1.0f : 0.0f;
        *(float4*)&orow[tx * 4]      = o0;
        *(float4*)&orow[tx * 4 + 64] = o1;
    }
}

extern "C" void kernel_launch(void* const* d_in, const int* in_sizes, int n_in,
                              void* d_out, int out_size, void* d_ws, size_t ws_size,
                              hipStream_t stream) {
    const float* in = (const float*)d_in[0];  // [128,512,256]
    const float* w  = (const float*)d_in[1];  // [512,1024]
    float* out      = (float*)d_out;          // [128,1024,256]

    dim3 grid(TT / 128, UU / 128, BB);  // (2, 8, 128) = 2048 blocks
    snn_gemm_kernel<<<grid, dim3(256), 0, stream>>>(in, w, out);
}